// Round 6
// baseline (564.741 us; speedup 1.0000x reference)
//
#include <hip/hip_runtime.h>
#include <hip/hip_fp16.h>
#include <math.h>

#define IN0    128
#define HEADS  4
#define CDIM   64
#define HC     256
#define SLOPE  0.2f
#define NPAD   50176   // 392*128, row padding
#define BK     32      // k-chunk (halves) = 64 B

typedef __attribute__((ext_vector_type(8))) _Float16 f16x8;
typedef __attribute__((ext_vector_type(4))) float f32x4;
typedef __attribute__((ext_vector_type(4))) uint  uintv4;
typedef __attribute__((ext_vector_type(4))) float fltv4;
typedef __attribute__((ext_vector_type(4))) ushort usv4;

__device__ __forceinline__ float h2f(ushort u) {
    __half h = *(const __half*)&u;
    return __half2float(h);
}
__device__ __forceinline__ ushort f2h(float f) {
    __half h = __float2half_rn(f);
    return *(ushort*)&h;
}

// ---------------- fused prep: degree + xconv(fp16,chunked) + wconv(fp16,chunked) x3 ----------------

__device__ __forceinline__ void wconv_body(const float* __restrict__ W,
                                           ushort* __restrict__ Wc, int K, int b) {
    int tid = b * 256 + threadIdx.x;     // K*256 threads
    int n = tid & 255;                   // output col (coalesced read)
    int k = tid >> 8;
    if (k >= K) return;
    Wc[(size_t)(k >> 5) * (HC * BK) + n * BK + (k & 31)] = f2h(W[(size_t)k * HC + n]);
}

__global__ __launch_bounds__(256) void k_prep(
        const int* __restrict__ dst_rand, int E_rand, int* __restrict__ deg,
        const float* __restrict__ x0, ushort* __restrict__ Xc, int totalx,
        const float* __restrict__ W0, ushort* __restrict__ Wc0,
        const float* __restrict__ W1, ushort* __restrict__ Wc1,
        const float* __restrict__ W2, ushort* __restrict__ Wc2,
        int B0, int B1) {
    int b = blockIdx.x;
    if (b < B0) {
        int i = b * 256 + threadIdx.x;
        if (i < E_rand) atomicAdd(&deg[dst_rand[i]], 1);
        return;
    }
    b -= B0;
    if (b < B1) {                        // xconv: x0 [N][128] -> Xc [4][NPAD][32]
        int i = b * 256 + threadIdx.x;
        if (i < totalx) {
            int n = i >> 7, k = i & 127;
            Xc[(size_t)(k >> 5) * (NPAD * BK) + n * BK + (k & 31)] = f2h(x0[i]);
        }
        return;
    }
    b -= B1;
    if (b < 128) { wconv_body(W0, Wc0, 128, b); return; }
    b -= 128;
    if (b < 256) { wconv_body(W1, Wc1, 256, b); return; }
    b -= 256;
    wconv_body(W2, Wc2, 256, b);
}

// ---------------- scan over PADDED degrees: rowptrp[n], segments padded to x8 ----------------

__global__ __launch_bounds__(1024) void k_scan(const int* __restrict__ deg, int Nn,
                                               int* __restrict__ rowptrp,
                                               int* __restrict__ cur) {
    __shared__ int smem[1024];
    int tid = threadIdx.x;
    int pre = 0;
    int limit = blockIdx.x * 1024;
    for (int i = tid; i < limit; i += 1024) pre += (deg[i] + 7) & ~7;
    smem[tid] = pre;
    __syncthreads();
    #pragma unroll
    for (int d = 512; d >= 1; d >>= 1) {
        if (tid < d) smem[tid] += smem[tid + d];
        __syncthreads();
    }
    int s_off = smem[0];
    __syncthreads();
    int i = blockIdx.x * 1024 + tid;
    int v = (i < Nn) ? ((deg[i] + 7) & ~7) : 0;
    smem[tid] = v;
    __syncthreads();
    #pragma unroll
    for (int d = 1; d < 1024; d <<= 1) {
        int t = 0;
        if (tid >= d) t = smem[tid - d];
        __syncthreads();
        smem[tid] += t;
        __syncthreads();
    }
    if (i < Nn) {
        int e = s_off + smem[tid] - v;
        rowptrp[i] = e;
        cur[i] = e;
    }
    if (blockIdx.x == gridDim.x - 1 && tid == 1023) rowptrp[Nn] = s_off + smem[1023];
}

__global__ void k_scatter(const int* __restrict__ src, const int* __restrict__ dst, int E_rand,
                          int* __restrict__ cur,
                          ushort* __restrict__ csr_src16,
                          ushort* __restrict__ csr_dst16) {
    int i = blockIdx.x * blockDim.x + threadIdx.x;
    if (i < E_rand) {
        int d = dst[i];
        int p = atomicAdd(&cur[d], 1);
        csr_src16[p] = (ushort)src[i];
        csr_dst16[p] = (ushort)d;      // Nn = 50000 < 65535; 0xFFFF = pad sentinel
    }
}

// ---------------- fused GEMM + attention scores (fp16 MFMA, no LDS, chunked operands) ----------------
// H output is stored CHUNKED [HC/32][NPAD][32] so the aggregate can slice it per-XCD.
// a_src/a_dst are stored INTERLEAVED [Nn][4 heads] so k_edgew gets all heads in one line.

template<int K>
__global__ __launch_bounds__(256) void k_gemm_att(const ushort* __restrict__ Xc,
                                                  const ushort* __restrict__ Wc,
                                                  const float* __restrict__ attS,
                                                  const float* __restrict__ attD,
                                                  ushort* __restrict__ H16out,
                                                  float* __restrict__ a_src_v,
                                                  float* __restrict__ a_dst_v,
                                                  int M) {
    int id    = blockIdx.x;
    int group = id >> 4;
    int sub   = id & 15;
    int row0  = (group * 8 + (sub & 7)) * 128;
    int colb  = sub >> 3;
    int col0  = colb * 128;

    int t    = threadIdx.x;
    int wave = t >> 6, lane = t & 63;
    int wm = wave & 1, wn = wave >> 1;
    int quad = lane >> 4, l16 = lane & 15;

    f32x4 acc[4][4];
    #pragma unroll
    for (int i = 0; i < 4; i++)
        #pragma unroll
        for (int j = 0; j < 4; j++) acc[i][j] = (f32x4){0.f, 0.f, 0.f, 0.f};

    constexpr int NK = K / BK;
    #pragma unroll
    for (int kc = 0; kc < NK; kc++) {
        f16x8 a[4], b[4];
        #pragma unroll
        for (int mt = 0; mt < 4; mt++) {
            size_t ga = (size_t)kc * (NPAD * BK)
                      + (size_t)(row0 + wm * 64 + mt * 16 + l16) * BK + quad * 8;
            a[mt] = *(const f16x8*)&Xc[ga];
        }
        #pragma unroll
        for (int nt = 0; nt < 4; nt++) {
            size_t gb = (size_t)kc * (HC * BK)
                      + (size_t)(col0 + wn * 64 + nt * 16 + l16) * BK + quad * 8;
            b[nt] = *(const f16x8*)&Wc[gb];
        }
        #pragma unroll
        for (int mt = 0; mt < 4; mt++)
            #pragma unroll
            for (int nt = 0; nt < 4; nt++)
                acc[mt][nt] = __builtin_amdgcn_mfma_f32_16x16x32_f16(a[mt], b[nt], acc[mt][nt], 0, 0, 0);
    }

    // epilogue 1: store H as fp16 CHUNKED (C/D layout col=lane&15, row=quad*4+reg)
    #pragma unroll
    for (int mt = 0; mt < 4; mt++) {
        #pragma unroll
        for (int r = 0; r < 4; r++) {
            int row = row0 + wm*64 + mt*16 + quad*4 + r;
            if (row >= M) continue;
            #pragma unroll
            for (int nt = 0; nt < 4; nt++) {
                int col = col0 + wn*64 + nt*16 + l16;
                size_t idx = (size_t)(col >> 5) * (NPAD * 32) + (size_t)row * 32 + (col & 31);
                H16out[idx] = f2h(acc[mt][nt][r]);
            }
        }
    }

    // epilogue 2: att score dots; this wave's cols = head (2*colb + wn).
    int headw = colb * 2 + wn;
    float sS[4], sD[4];
    #pragma unroll
    for (int nt = 0; nt < 4; nt++) {
        sS[nt] = attS[headw * CDIM + nt*16 + l16];
        sD[nt] = attD[headw * CDIM + nt*16 + l16];
    }
    #pragma unroll
    for (int mt = 0; mt < 4; mt++) {
        #pragma unroll
        for (int r = 0; r < 4; r++) {
            float ps = 0.f, pd = 0.f;
            #pragma unroll
            for (int nt = 0; nt < 4; nt++) {
                float av = acc[mt][nt][r];
                ps += av * sS[nt];
                pd += av * sD[nt];
            }
            #pragma unroll
            for (int d = 1; d <= 8; d <<= 1) {
                ps += __shfl_xor(ps, d);
                pd += __shfl_xor(pd, d);
            }
            int row = row0 + wm*64 + mt*16 + quad*4 + r;
            if (l16 == 0 && row < M) {
                a_src_v[(size_t)row * 4 + headw] = ps;   // interleaved [n][4]
                a_dst_v[(size_t)row * 4 + headw] = pd;
            }
        }
    }
}

// ---------------- edge weights: w[h][p] = exp(leaky(a_src[src]+a_dst[dst])) ----------------
// Edge-parallel, coalesced; pad slots (csr_dst16==0xFFFF) keep their memset-0 weight.

__global__ __launch_bounds__(256) void k_edgew(
        const ushort* __restrict__ csr_src16, const ushort* __restrict__ csr_dst16,
        const float* __restrict__ aI_src, const float* __restrict__ aI_dst,
        float* __restrict__ wpl, int EPM) {
    int p = blockIdx.x * 256 + threadIdx.x;
    if (p >= EPM) return;
    ushort d16 = csr_dst16[p];
    if (d16 == 0xFFFFu) return;          // pad slot: w stays 0
    int s = csr_src16[p], d = d16;
    float4 as = *(const float4*)&aI_src[(size_t)s * 4];
    float4 ad = *(const float4*)&aI_dst[(size_t)d * 4];
    float e0 = as.x + ad.x, e1 = as.y + ad.y, e2 = as.z + ad.z, e3 = as.w + ad.w;
    e0 = fmaxf(e0, SLOPE * e0); e1 = fmaxf(e1, SLOPE * e1);
    e2 = fmaxf(e2, SLOPE * e2); e3 = fmaxf(e3, SLOPE * e3);
    wpl[0 * (size_t)EPM + p] = __expf(e0);
    wpl[1 * (size_t)EPM + p] = __expf(e1);
    wpl[2 * (size_t)EPM + p] = __expf(e2);
    wpl[3 * (size_t)EPM + p] = __expf(e3);
}

// ---------------- aggregation: XCD-sliced, padded CSR, ping-pong 2-stage pipeline ----------------
// slice = blockIdx%8 -> XCD affinity; each XCD's L2 holds its 3.2 MB H-slice.
// Lane = node_sub(3b) x ch-quad(3b); acc/ssum lane-private, zero shuffles.
// r5 fixes: (1) CSR segments padded to x8 with (s=0,w=0) pad entries -> NO masking
// instructions, no max-deg shuffle; per-8-lane-group divergent loop over own degp.
// (2) ping-pong X/Y banks: batch k's gathers are issued one full body before their
// consumption -> one consume-phase (~130cy) of latency slack per gather batch.
// (3) csr as ushort (ids < 65536) halves the index stream.

__device__ __forceinline__ void eacc(float w, ushort4 u, float& ss, float4& a) {
    ss += w;
    a.x = fmaf(w, h2f(u.x), a.x);
    a.y = fmaf(w, h2f(u.y), a.y);
    a.z = fmaf(w, h2f(u.z), a.z);
    a.w = fmaf(w, h2f(u.w), a.w);
}

__global__ __launch_bounds__(256) void k_aggregate(
        const ushort* __restrict__ Hc,      // chunked fp16 [8][NPAD][32]
        const float* __restrict__ aI_src,   // [Nn][4] interleaved (self-loop only)
        const float* __restrict__ aI_dst,   // [Nn][4]
        const int* __restrict__ rowptrp,    // padded rowptr (multiples of 8)
        const ushort* __restrict__ csr16,   // padded src ids (+64 slack)
        const float* __restrict__ wpl, int EPM,
        const float* __restrict__ bias,
        float* __restrict__ out_f32,        // nullable
        ushort* __restrict__ out_h16c,      // nullable (fp16, CHUNKED)
        int Nn) {
    int lane  = threadIdx.x & 63;
    int wave  = threadIdx.x >> 6;
    int slice = blockIdx.x & 7;             // == XCD under round-robin dispatch
    int c8    = lane & 7;                   // channel quad: ch = slice*32 + c8*4
    int nsub  = lane >> 3;                  // node within wave (0..7)
    int n = (blockIdx.x >> 3) * 32 + wave * 8 + nsub;
    bool nvalid = (n < Nn);
    int nc = nvalid ? n : (Nn - 1);

    int h = slice >> 1;
    const ushort* Hs = Hc + (size_t)slice * (NPAD * 32);   // block-uniform base (SGPR)
    const float* wh = wpl + (size_t)h * EPM;

    int begp = rowptrp[nc];
    int dp   = rowptrp[nc + 1] - begp;      // padded degree (multiple of 8)
    if (!nvalid) dp = 0;

    uint c8u = (uint)(c8 * 4);              // ushort-unit offset within 32-ushort row
    const ushort* cp = csr16 + begp;
    const float*  wp = wh + begp;

    float ssum = 0.f;
    float4 acc = make_float4(0.f, 0.f, 0.f, 0.f);

#define GATHER8(SV, U0,U1,U2,U3,U4,U5,U6,U7) do {                          \
        uint _a = SV.x, _b = SV.y, _c = SV.z, _d = SV.w;                   \
        U0 = *(const ushort4*)(Hs + (_a & 0xFFFFu) * 32u + c8u);           \
        U1 = *(const ushort4*)(Hs + (_a >> 16)     * 32u + c8u);           \
        U2 = *(const ushort4*)(Hs + (_b & 0xFFFFu) * 32u + c8u);           \
        U3 = *(const ushort4*)(Hs + (_b >> 16)     * 32u + c8u);           \
        U4 = *(const ushort4*)(Hs + (_c & 0xFFFFu) * 32u + c8u);           \
        U5 = *(const ushort4*)(Hs + (_c >> 16)     * 32u + c8u);           \
        U6 = *(const ushort4*)(Hs + (_d & 0xFFFFu) * 32u + c8u);           \
        U7 = *(const ushort4*)(Hs + (_d >> 16)     * 32u + c8u);           \
    } while (0)

#define CONSUME(Wa, Wb, U0,U1,U2,U3,U4,U5,U6,U7) do {                      \
        eacc(Wa.x, U0, ssum, acc); eacc(Wa.y, U1, ssum, acc);              \
        eacc(Wa.z, U2, ssum, acc); eacc(Wa.w, U3, ssum, acc);              \
        eacc(Wb.x, U4, ssum, acc); eacc(Wb.y, U5, ssum, acc);              \
        eacc(Wb.z, U6, ssum, acc); eacc(Wb.w, U7, ssum, acc);              \
    } while (0)

    // prologue: bank X = batch 0, bank Y staged for batch 8
    uintv4 SX = __builtin_nontemporal_load((const uintv4*)(cp));
    uintv4 SY = __builtin_nontemporal_load((const uintv4*)(cp + 8));
    fltv4 WXa = __builtin_nontemporal_load((const fltv4*)(wp));
    fltv4 WXb = __builtin_nontemporal_load((const fltv4*)(wp + 4));
    fltv4 WYa, WYb;
    ushort4 X0, X1, X2, X3, X4, X5, X6, X7;
    ushort4 Y0, Y1, Y2, Y3, Y4, Y5, Y6, Y7;
    GATHER8(SX, X0, X1, X2, X3, X4, X5, X6, X7);

    for (int i = 0; i < dp; i += 16) {
        // even body: consume batch i (X), issue batch i+8 (Y), stage i+16
        SX  = __builtin_nontemporal_load((const uintv4*)(cp + i + 16));
        GATHER8(SY, Y0, Y1, Y2, Y3, Y4, Y5, Y6, Y7);
        WYa = __builtin_nontemporal_load((const fltv4*)(wp + i + 8));
        WYb = __builtin_nontemporal_load((const fltv4*)(wp + i + 12));
        CONSUME(WXa, WXb, X0, X1, X2, X3, X4, X5, X6, X7);
        if (i + 8 < dp) {
            // odd body: consume batch i+8 (Y), issue batch i+16 (X), stage i+24
            SY  = __builtin_nontemporal_load((const uintv4*)(cp + i + 24));
            GATHER8(SX, X0, X1, X2, X3, X4, X5, X6, X7);
            WXa = __builtin_nontemporal_load((const fltv4*)(wp + i + 16));
            WXb = __builtin_nontemporal_load((const fltv4*)(wp + i + 20));
            CONSUME(WYa, WYb, Y0, Y1, Y2, Y3, Y4, Y5, Y6, Y7);
        }
    }
#undef GATHER8
#undef CONSUME

    // self-loop + epilogue (all lane-private)
    float es = aI_src[(size_t)nc * 4 + h] + aI_dst[(size_t)nc * 4 + h];
    es = fmaxf(es, SLOPE * es);
    float exs = __expf(es);
    ushort4 us = *(const ushort4*)(Hs + (uint)nc * 32u + c8u);
    float rden = 1.f / (ssum + exs + 1e-16f);
    int ch = slice * 32 + c8 * 4;
    float4 b = *(const float4*)&bias[ch];
    float4 o4;
    o4.x = fmaxf((acc.x + exs * h2f(us.x)) * rden + b.x, 0.f);
    o4.y = fmaxf((acc.y + exs * h2f(us.y)) * rden + b.y, 0.f);
    o4.z = fmaxf((acc.z + exs * h2f(us.z)) * rden + b.z, 0.f);
    o4.w = fmaxf((acc.w + exs * h2f(us.w)) * rden + b.w, 0.f);

    if (nvalid) {
        if (out_f32) {
            // 8 c8-lanes x 16B = 128B full line per node, 8 nodes contiguous
            fltv4 ov = {o4.x, o4.y, o4.z, o4.w};
            __builtin_nontemporal_store(ov, (fltv4*)&out_f32[(size_t)n * HC + ch]);
        }
        if (out_h16c) {
            size_t idx = (size_t)slice * (NPAD * 32) + (size_t)n * 32 + c8 * 4;
            usv4 ou = {f2h(o4.x), f2h(o4.y), f2h(o4.z), f2h(o4.w)};
            __builtin_nontemporal_store(ou, (usv4*)&out_h16c[idx]);
        }
    }
}

// ---------------- launch ----------------

extern "C" void kernel_launch(void* const* d_in, const int* in_sizes, int n_in,
                              void* d_out, int out_size, void* d_ws, size_t ws_size,
                              hipStream_t stream) {
    const float* x0   = (const float*)d_in[0];
    const int*   eidx = (const int*)d_in[1];
    int Nn = in_sizes[0] / IN0;     // 50000
    int E  = in_sizes[1] / 2;       // 850000
    int E_rand = E - Nn;            // 800000 random edges; self-loops inline
    const int* srcp = eidx;
    const int* dstp = eidx + E;

    const float* Wl[3]    = {(const float*)d_in[2],  (const float*)d_in[6],  (const float*)d_in[10]};
    const float* attS[3]  = {(const float*)d_in[3],  (const float*)d_in[7],  (const float*)d_in[11]};
    const float* attD[3]  = {(const float*)d_in[4],  (const float*)d_in[8],  (const float*)d_in[12]};
    const float* biasl[3] = {(const float*)d_in[5],  (const float*)d_in[9],  (const float*)d_in[13]};
    int Kdims[3] = {IN0, HC, HC};

    // worst-case padded edge count: every node pads +7, plus pipeline slack
    int EPM = E_rand + 7 * Nn + 64;

    // workspace carve
    char* p = (char*)d_ws;
    ushort* h16    = (ushort*)p; p += (size_t)NPAD * HC * sizeof(ushort);   // chunked [8][NPAD][32]
    ushort* Xc     = (ushort*)p; p += (size_t)NPAD * HC * sizeof(ushort);   // chunked
    float*  a_src_v= (float*)p;  p += (size_t)Nn * HEADS * sizeof(float);   // [Nn][4] interleaved
    float*  a_dst_v= (float*)p;  p += (size_t)Nn * HEADS * sizeof(float);   // [Nn][4] interleaved
    int*    rowptrp= (int*)p;    p += (size_t)(Nn + 1) * sizeof(int);
    int*    deg    = (int*)p;    p += (size_t)Nn * sizeof(int);
    int*    cur    = (int*)p;    p += (size_t)Nn * sizeof(int);
    ushort* csr_s16= (ushort*)p; p += (size_t)EPM * sizeof(ushort);
    ushort* csr_d16= (ushort*)p; p += (size_t)EPM * sizeof(ushort);
    float*  wpl    = (float*)p;  p += (size_t)HEADS * EPM * sizeof(float);  // [4][EPM]
    ushort* Wc[3];
    for (int l = 0; l < 3; l++) {
        Wc[l] = (ushort*)p; p += (size_t)HC * Kdims[l] * sizeof(ushort);
    }

    int NB = (Nn + 1023) / 1024;
    int B0 = (E_rand + 255) / 256;
    int B1 = (Nn * IN0 + 255) / 256;
    int Bprep = B0 + B1 + 128 + 256 + 256;

    hipMemsetAsync(deg, 0, (size_t)Nn * sizeof(int), stream);
    hipMemsetAsync(csr_s16, 0, (size_t)EPM * sizeof(ushort), stream);       // pads: s=0 (hot row)
    hipMemsetAsync(csr_d16, 0xFF, (size_t)EPM * sizeof(ushort), stream);    // pads: sentinel
    hipMemsetAsync(wpl, 0, (size_t)HEADS * EPM * sizeof(float), stream);    // pads: w=0
    k_prep<<<Bprep, 256, 0, stream>>>(dstp, E_rand, deg,
                                      x0, Xc, Nn * IN0,
                                      Wl[0], Wc[0], Wl[1], Wc[1], Wl[2], Wc[2],
                                      B0, B1);
    k_scan<<<NB, 1024, 0, stream>>>(deg, Nn, rowptrp, cur);
    k_scatter<<<(E_rand + 255) / 256, 256, 0, stream>>>(srcp, dstp, E_rand, cur,
                                                        csr_s16, csr_d16);

    dim3 g(784);                 // 49 groups x (8 row-blocks x 2 col-blocks), XCD-swizzled
    dim3 ge((EPM + 255) / 256);
    dim3 ga(8 * ((Nn + 31) / 32)); // (slice x node-group); slice = bid%8 -> XCD affinity
    for (int l = 0; l < 3; l++) {
        if (l == 0)
            k_gemm_att<128><<<g, 256, 0, stream>>>(Xc, Wc[l], attS[l], attD[l],
                                                   h16, a_src_v, a_dst_v, Nn);
        else
            k_gemm_att<256><<<g, 256, 0, stream>>>(Xc, Wc[l], attS[l], attD[l],
                                                   h16, a_src_v, a_dst_v, Nn);
        k_edgew<<<ge, 256, 0, stream>>>(csr_s16, csr_d16, a_src_v, a_dst_v, wpl, EPM);
        if (l < 2) {
            k_aggregate<<<ga, 256, 0, stream>>>(h16, a_src_v, a_dst_v, rowptrp, csr_s16,
                                                wpl, EPM, biasl[l], nullptr, Xc, Nn);
        } else {
            k_aggregate<<<ga, 256, 0, stream>>>(h16, a_src_v, a_dst_v, rowptrp, csr_s16,
                                                wpl, EPM, biasl[l], (float*)d_out, nullptr, Nn);
        }
    }
}

// Round 8
// 394.191 us; speedup vs baseline: 1.4327x; 1.4327x over previous
//
#include <hip/hip_runtime.h>
#include <hip/hip_fp16.h>
#include <math.h>

#define IN0    128
#define HEADS  4
#define CDIM   64
#define HC     256
#define SLOPE  0.2f
#define NPAD   50176   // 392*128, row padding
#define BK     32      // k-chunk (halves) = 64 B

typedef __attribute__((ext_vector_type(8))) _Float16 f16x8;
typedef __attribute__((ext_vector_type(4))) float f32x4;

__device__ __forceinline__ float h2f(ushort u) {
    __half h = *(const __half*)&u;
    return __half2float(h);
}
__device__ __forceinline__ ushort f2h(float f) {
    __half h = __float2half_rn(f);
    return *(ushort*)&h;
}

// ---------------- fused prep: degree + xconv(fp16,chunked) + wconv(fp16,chunked) x3 ----------------

__device__ __forceinline__ void wconv_body(const float* __restrict__ W,
                                           ushort* __restrict__ Wc, int K, int b) {
    int tid = b * 256 + threadIdx.x;     // K*256 threads
    int n = tid & 255;                   // output col (coalesced read)
    int k = tid >> 8;
    if (k >= K) return;
    Wc[(size_t)(k >> 5) * (HC * BK) + n * BK + (k & 31)] = f2h(W[(size_t)k * HC + n]);
}

__global__ __launch_bounds__(256) void k_prep(
        const int* __restrict__ dst_rand, int E_rand, int* __restrict__ deg,
        const float* __restrict__ x0, ushort* __restrict__ Xc, int totalx,
        const float* __restrict__ W0, ushort* __restrict__ Wc0,
        const float* __restrict__ W1, ushort* __restrict__ Wc1,
        const float* __restrict__ W2, ushort* __restrict__ Wc2,
        int B0, int B1) {
    int b = blockIdx.x;
    if (b < B0) {
        int i = b * 256 + threadIdx.x;
        if (i < E_rand) atomicAdd(&deg[dst_rand[i]], 1);
        return;
    }
    b -= B0;
    if (b < B1) {                        // xconv: x0 [N][128] -> Xc [4][NPAD][32]
        int i = b * 256 + threadIdx.x;
        if (i < totalx) {
            int n = i >> 7, k = i & 127;
            Xc[(size_t)(k >> 5) * (NPAD * BK) + n * BK + (k & 31)] = f2h(x0[i]);
        }
        return;
    }
    b -= B1;
    if (b < 128) { wconv_body(W0, Wc0, 128, b); return; }
    b -= 128;
    if (b < 256) { wconv_body(W1, Wc1, 256, b); return; }
    b -= 256;
    wconv_body(W2, Wc2, 256, b);
}

// ---------------- single-kernel scan (prefix-of-prefixes brute force) ----------------

__global__ __launch_bounds__(1024) void k_scan(const int* __restrict__ deg, int Nn,
                                               int* __restrict__ rowptr,
                                               int* __restrict__ cur) {
    __shared__ int smem[1024];
    int tid = threadIdx.x;
    int pre = 0;
    int limit = blockIdx.x * 1024;
    for (int i = tid; i < limit; i += 1024) pre += deg[i];
    smem[tid] = pre;
    __syncthreads();
    #pragma unroll
    for (int d = 512; d >= 1; d >>= 1) {
        if (tid < d) smem[tid] += smem[tid + d];
        __syncthreads();
    }
    int s_off = smem[0];
    __syncthreads();
    int i = blockIdx.x * 1024 + tid;
    int v = (i < Nn) ? deg[i] : 0;
    smem[tid] = v;
    __syncthreads();
    #pragma unroll
    for (int d = 1; d < 1024; d <<= 1) {
        int t = 0;
        if (tid >= d) t = smem[tid - d];
        __syncthreads();
        smem[tid] += t;
        __syncthreads();
    }
    if (i < Nn) {
        int e = s_off + smem[tid] - v;
        rowptr[i] = e;
        cur[i] = e;
    }
    if (blockIdx.x == gridDim.x - 1 && tid == 1023) rowptr[Nn] = s_off + smem[1023];
}

__global__ void k_scatter(const int* __restrict__ src, const int* __restrict__ dst, int E_rand,
                          int* __restrict__ cur, int* __restrict__ csr_src) {
    int i = blockIdx.x * blockDim.x + threadIdx.x;
    if (i < E_rand) {
        int d = dst[i];
        int p = atomicAdd(&cur[d], 1);
        csr_src[p] = src[i];
    }
}

// ---------------- fused GEMM + attention scores (fp16 MFMA, no LDS, chunked operands) ----------------
// Identical to the proven r0 kernel: H row-major [NPAD][HC], a-tables interleaved [n][4].

template<int K>
__global__ __launch_bounds__(256) void k_gemm_att(const ushort* __restrict__ Xc,
                                                  const ushort* __restrict__ Wc,
                                                  const float* __restrict__ attS,
                                                  const float* __restrict__ attD,
                                                  ushort* __restrict__ H16out,
                                                  float* __restrict__ a_src_v,
                                                  float* __restrict__ a_dst_v,
                                                  int M) {
    int id    = blockIdx.x;
    int group = id >> 4;
    int sub   = id & 15;
    int row0  = (group * 8 + (sub & 7)) * 128;
    int colb  = sub >> 3;
    int col0  = colb * 128;

    int t    = threadIdx.x;
    int wave = t >> 6, lane = t & 63;
    int wm = wave & 1, wn = wave >> 1;
    int quad = lane >> 4, l16 = lane & 15;

    f32x4 acc[4][4];
    #pragma unroll
    for (int i = 0; i < 4; i++)
        #pragma unroll
        for (int j = 0; j < 4; j++) acc[i][j] = (f32x4){0.f, 0.f, 0.f, 0.f};

    constexpr int NK = K / BK;
    #pragma unroll
    for (int kc = 0; kc < NK; kc++) {
        f16x8 a[4], b[4];
        #pragma unroll
        for (int mt = 0; mt < 4; mt++) {
            size_t ga = (size_t)kc * (NPAD * BK)
                      + (size_t)(row0 + wm * 64 + mt * 16 + l16) * BK + quad * 8;
            a[mt] = *(const f16x8*)&Xc[ga];
        }
        #pragma unroll
        for (int nt = 0; nt < 4; nt++) {
            size_t gb = (size_t)kc * (HC * BK)
                      + (size_t)(col0 + wn * 64 + nt * 16 + l16) * BK + quad * 8;
            b[nt] = *(const f16x8*)&Wc[gb];
        }
        #pragma unroll
        for (int mt = 0; mt < 4; mt++)
            #pragma unroll
            for (int nt = 0; nt < 4; nt++)
                acc[mt][nt] = __builtin_amdgcn_mfma_f32_16x16x32_f16(a[mt], b[nt], acc[mt][nt], 0, 0, 0);
    }

    // epilogue 1: store H as fp16 row-major (C/D layout col=lane&15, row=quad*4+reg)
    #pragma unroll
    for (int mt = 0; mt < 4; mt++) {
        #pragma unroll
        for (int r = 0; r < 4; r++) {
            int row = row0 + wm*64 + mt*16 + quad*4 + r;
            if (row >= M) continue;
            #pragma unroll
            for (int nt = 0; nt < 4; nt++) {
                size_t idx = (size_t)row * HC + col0 + wn*64 + nt*16 + l16;
                H16out[idx] = f2h(acc[mt][nt][r]);
            }
        }
    }

    // epilogue 2: att score dots; this wave's cols = head (2*colb + wn).
    int headw = colb * 2 + wn;
    float sS[4], sD[4];
    #pragma unroll
    for (int nt = 0; nt < 4; nt++) {
        sS[nt] = attS[headw * CDIM + nt*16 + l16];
        sD[nt] = attD[headw * CDIM + nt*16 + l16];
    }
    #pragma unroll
    for (int mt = 0; mt < 4; mt++) {
        #pragma unroll
        for (int r = 0; r < 4; r++) {
            float ps = 0.f, pd = 0.f;
            #pragma unroll
            for (int nt = 0; nt < 4; nt++) {
                float av = acc[mt][nt][r];
                ps += av * sS[nt];
                pd += av * sD[nt];
            }
            #pragma unroll
            for (int d = 1; d <= 8; d <<= 1) {
                ps += __shfl_xor(ps, d);
                pd += __shfl_xor(pd, d);
            }
            int row = row0 + wm*64 + mt*16 + quad*4 + r;
            if (l16 == 0 && row < M) {
                a_src_v[row * HEADS + headw] = ps;
                a_dst_v[row * HEADS + headw] = pd;
            }
        }
    }
}

// ---------------- aggregation: r0 wave structure, S=2 channel halves with XCD parity ----------------
// Wave = (node, half); slice = blockIdx&1 -> even XCDs process channels 0-127 (heads 0,1),
// odd XCDs 128-255 (heads 2,3) under round-robin dispatch: per-XCD distinct H bytes
// halve (25.7 -> 12.8 MB) -> compulsory FETCH ~halves vs r0's 210 MB.
// Gather shape kept from the proven r0 kernel: contiguous 256 B per edge, 2 edges per
// 64-lane instruction (512 B/instr, same instruction count per edge as r0).
// ex phase: 32 edge slots x 2 heads per wave (half the broadcast work of r0's 16x4).

__global__ __launch_bounds__(256) void k_aggregate(
        const ushort* __restrict__ H16,     // [NPAD][HC] fp16 row-major
        const float* __restrict__ a_src_v,  // [Nn][4]
        const float* __restrict__ a_dst_v,  // [Nn][4]
        const int* __restrict__ rowptr, const int* __restrict__ csr_src,
        const float* __restrict__ bias,
        float* __restrict__ out_f32,        // nullable
        ushort* __restrict__ out_h16c,      // nullable (fp16, CHUNKED for next GEMM)
        int Nn) {
    int wave  = threadIdx.x >> 6;
    int lane  = threadIdx.x & 63;
    int slice = blockIdx.x & 1;             // channel half == XCD parity
    int n = (blockIdx.x >> 1) * 4 + wave;
    if (n >= Nn) return;

    // ex phase: 32 edge slots x 2 heads
    int e32 = lane >> 1;                    // edge slot 0..31
    int hs2 = lane & 1;                     // head within half
    int hgl = slice * 2 + hs2;              // global head
    // acc phase: 2 edges x (2 heads x 16 ch-quads)
    int e2  = lane >> 5;                    // edge sub-slot 0/1
    int ha2 = (lane >> 4) & 1;              // head within half
    int c4  = (lane & 15) * 4;              // channel base within head
    int chS = ha2 * CDIM + c4;              // channel within half (0..124)

    int beg = rowptr[n], end = rowptr[n + 1];
    int deg = end - beg;
    float adst_s = a_dst_v[n * HEADS + hgl];
    float es = a_src_v[n * HEADS + hgl] + adst_s;
    es = fmaxf(es, SLOPE * es);
    float ex_self_s = __expf(es);

    float ssum = 0.f;
    float4 acc = make_float4(0.f, 0.f, 0.f, 0.f);
    const char* Hb = (const char*)H16 + (size_t)(slice * 128 + chS) * 2;

    for (int base = 0; base < deg; base += 32) {
        int cnt = min(32, deg - base);
        int s_l = 0; float ex_l = 0.f;
        if (e32 < cnt) {
            s_l = csr_src[beg + base + e32];
            float e = a_src_v[s_l * HEADS + hgl] + adst_s;
            e = fmaxf(e, SLOPE * e);
            ex_l = __expf(e);
            ssum += ex_l;
        }
        int off_l = s_l * (HC * 2);         // row byte offset
        int cnt4 = (cnt + 3) & ~3;          // OOB slots: ex=0, off=0 (hot line)
        for (int j = 0; j < cnt4; j += 4) {
            // gather lane (e2,ha2,c4) <- edge j+e2 / j+2+e2, head ha2
            int sl0 = ((j + e2) << 1) | ha2;
            int sl1 = ((j + 2 + e2) << 1) | ha2;
            float a0 = __shfl(ex_l,  sl0);
            int   o0 = __shfl(off_l, sl0);
            float a1 = __shfl(ex_l,  sl1);
            int   o1 = __shfl(off_l, sl1);
            ushort4 u0 = *(const ushort4*)(Hb + o0);
            ushort4 u1 = *(const ushort4*)(Hb + o1);
            acc.x += a0 * h2f(u0.x); acc.y += a0 * h2f(u0.y);
            acc.z += a0 * h2f(u0.z); acc.w += a0 * h2f(u0.w);
            acc.x += a1 * h2f(u1.x); acc.y += a1 * h2f(u1.y);
            acc.z += a1 * h2f(u1.z); acc.w += a1 * h2f(u1.w);
        }
    }
    // denom: reduce over edge slots (lane bits 1..5); head bit (0) preserved
    #pragma unroll
    for (int d = 2; d <= 32; d <<= 1) ssum += __shfl_xor(ssum, d);
    ssum += ex_self_s;
    // acc: reduce over the e2 split (bit 5); lanes 0..31 hold full sums
    acc.x += __shfl_xor(acc.x, 32);
    acc.y += __shfl_xor(acc.y, 32);
    acc.z += __shfl_xor(acc.z, 32);
    acc.w += __shfl_xor(acc.w, 32);
    // broadcast denom/self weight to acc-phase lanes: source lane = ha2 (0/1)
    float den_a = __shfl(ssum, ha2);
    float exs_a = __shfl(ex_self_s, ha2);

    ushort4 us = *(const ushort4*)((const char*)H16 + (size_t)n * (HC * 2)
                                   + (size_t)(slice * 128 + chS) * 2);
    float rden = 1.f / (den_a + 1e-16f);
    int ch = slice * 128 + chS;
    float4 b = *(const float4*)&bias[ch];
    float4 o;
    o.x = fmaxf((acc.x + exs_a * h2f(us.x)) * rden + b.x, 0.f);
    o.y = fmaxf((acc.y + exs_a * h2f(us.y)) * rden + b.y, 0.f);
    o.z = fmaxf((acc.z + exs_a * h2f(us.z)) * rden + b.z, 0.f);
    o.w = fmaxf((acc.w + exs_a * h2f(us.w)) * rden + b.w, 0.f);

    if (e2 == 0) {                          // lanes 0..31: 128 ch = 512B f32 contiguous
        if (out_f32) {
            *(float4*)&out_f32[(size_t)n * HC + ch] = o;
        }
        if (out_h16c) {
            size_t idx = (size_t)(ch >> 5) * (NPAD * BK) + (size_t)n * BK + (ch & 31);
            *(ushort4*)&out_h16c[idx] = make_ushort4(f2h(o.x), f2h(o.y), f2h(o.z), f2h(o.w));
        }
    }
}

// ---------------- launch ----------------

extern "C" void kernel_launch(void* const* d_in, const int* in_sizes, int n_in,
                              void* d_out, int out_size, void* d_ws, size_t ws_size,
                              hipStream_t stream) {
    const float* x0   = (const float*)d_in[0];
    const int*   eidx = (const int*)d_in[1];
    int Nn = in_sizes[0] / IN0;     // 50000
    int E  = in_sizes[1] / 2;       // 850000
    int E_rand = E - Nn;            // 800000 random edges; self-loops inline
    const int* srcp = eidx;
    const int* dstp = eidx + E;

    const float* Wl[3]    = {(const float*)d_in[2],  (const float*)d_in[6],  (const float*)d_in[10]};
    const float* attS[3]  = {(const float*)d_in[3],  (const float*)d_in[7],  (const float*)d_in[11]};
    const float* attD[3]  = {(const float*)d_in[4],  (const float*)d_in[8],  (const float*)d_in[12]};
    const float* biasl[3] = {(const float*)d_in[5],  (const float*)d_in[9],  (const float*)d_in[13]};
    int Kdims[3] = {IN0, HC, HC};

    // workspace carve
    char* p = (char*)d_ws;
    ushort* h16    = (ushort*)p; p += (size_t)NPAD * HC * sizeof(ushort);
    ushort* Xc     = (ushort*)p; p += (size_t)NPAD * HC * sizeof(ushort);   // chunked
    float*  a_src_v= (float*)p;  p += (size_t)Nn * HEADS * sizeof(float);
    float*  a_dst_v= (float*)p;  p += (size_t)Nn * HEADS * sizeof(float);
    int*    rowptr = (int*)p;    p += (size_t)(Nn + 1) * sizeof(int);
    int*    deg    = (int*)p;    p += (size_t)Nn * sizeof(int);
    int*    cur    = (int*)p;    p += (size_t)Nn * sizeof(int);
    int*    csr_src= (int*)p;    p += (size_t)E_rand * sizeof(int);
    ushort* Wc[3];
    for (int l = 0; l < 3; l++) {
        Wc[l] = (ushort*)p; p += (size_t)HC * Kdims[l] * sizeof(ushort);
    }

    int NB = (Nn + 1023) / 1024;
    int B0 = (E_rand + 255) / 256;
    int B1 = (Nn * IN0 + 255) / 256;
    int Bprep = B0 + B1 + 128 + 256 + 256;

    hipMemsetAsync(deg, 0, (size_t)Nn * sizeof(int), stream);
    k_prep<<<Bprep, 256, 0, stream>>>(dstp, E_rand, deg,
                                      x0, Xc, Nn * IN0,
                                      Wl[0], Wc[0], Wl[1], Wc[1], Wl[2], Wc[2],
                                      B0, B1);
    k_scan<<<NB, 1024, 0, stream>>>(deg, Nn, rowptr, cur);
    k_scatter<<<(E_rand + 255) / 256, 256, 0, stream>>>(srcp, dstp, E_rand, cur, csr_src);

    dim3 g(784);                   // 49 groups x (8 row-blocks x 2 col-blocks), XCD-swizzled
    dim3 ga(2 * ((Nn + 3) / 4));   // (node-group x half); half = bid&1 -> XCD parity
    for (int l = 0; l < 3; l++) {
        if (l == 0)
            k_gemm_att<128><<<g, 256, 0, stream>>>(Xc, Wc[l], attS[l], attD[l],
                                                   h16, a_src_v, a_dst_v, Nn);
        else
            k_gemm_att<256><<<g, 256, 0, stream>>>(Xc, Wc[l], attS[l], attD[l],
                                                   h16, a_src_v, a_dst_v, Nn);
        if (l < 2) {
            k_aggregate<<<ga, 256, 0, stream>>>(h16, a_src_v, a_dst_v, rowptr, csr_src,
                                                biasl[l], nullptr, Xc, Nn);
        } else {
            k_aggregate<<<ga, 256, 0, stream>>>(h16, a_src_v, a_dst_v, rowptr, csr_src,
                                                biasl[l], (float*)d_out, nullptr, Nn);
        }
    }
}